// Round 1
// baseline (47296.173 us; speedup 1.0000x reference)
//
#include <hip/hip_runtime.h>

// Problem dims
constexpr int kB    = 64;
constexpr int kT    = 512;
constexpr int kDin  = 256;
constexpr int kH    = 1024;
constexpr int kH3   = 3072;
constexpr int kDout = 256;

typedef float  f32x4  __attribute__((ext_vector_type(4)));
typedef __bf16 bf16x8 __attribute__((ext_vector_type(8)));

__device__ __forceinline__ float b2f(unsigned short u) {
  union { float f; unsigned u32; } c; c.u32 = ((unsigned)u) << 16; return c.f;
}
__device__ __forceinline__ unsigned short f2b(float f) {
  union { float f; unsigned u32; } c; c.f = f;
  unsigned r = c.u32 + 0x7fffu + ((c.u32 >> 16) & 1u);  // RNE
  return (unsigned short)(r >> 16);
}
__device__ __forceinline__ bf16x8 ld8(const unsigned short* p) {
  return *reinterpret_cast<const bf16x8*>(p);
}
__device__ __forceinline__ float sigmoidf_(float x) { return 1.f / (1.f + __expf(-x)); }

#define MFMA16(a, b, c) __builtin_amdgcn_mfma_f32_16x16x32_bf16((a), (b), (c), 0, 0, 0)

// ---------------------------------------------------------------------------
// Distributed-slot grid barrier: block b publishes its phase to slots[b]
// (release, agent scope); thread i of every block spins on slots[i]
// (grid == block == 256). No same-address RMW contention.
// ---------------------------------------------------------------------------
__device__ __forceinline__ void grid_barrier(unsigned* slots, unsigned phase) {
  __threadfence();      // release this thread's stores to device scope
  __syncthreads();      // all threads of block have fenced
  if (threadIdx.x == 0)
    __hip_atomic_store(&slots[blockIdx.x], phase, __ATOMIC_RELEASE,
                       __HIP_MEMORY_SCOPE_AGENT);
  while (__hip_atomic_load(&slots[threadIdx.x], __ATOMIC_RELAXED,
                           __HIP_MEMORY_SCOPE_AGENT) < phase)
    __builtin_amdgcn_s_sleep(1);
  __syncthreads();
  __threadfence();      // acquire: invalidate stale cached lines
}

// ---------------------------------------------------------------------------
// Prep: fp32->bf16 weight/x conversion, combined biases, zero state + slots.
// ---------------------------------------------------------------------------
__global__ void gru_prep(const float* __restrict__ x,
                         const float* __restrict__ Wi0, const float* __restrict__ Wh0,
                         const float* __restrict__ bi0, const float* __restrict__ bh0,
                         const float* __restrict__ Wi1, const float* __restrict__ Wh1,
                         const float* __restrict__ bi1, const float* __restrict__ bh1,
                         unsigned short* __restrict__ xb,
                         unsigned short* __restrict__ wi0b, unsigned short* __restrict__ wh0b,
                         unsigned short* __restrict__ wi1b, unsigned short* __restrict__ wh1b,
                         unsigned short* __restrict__ h0b, unsigned short* __restrict__ h1b,
                         float* __restrict__ bias, unsigned* __restrict__ slots) {
  const int stride = gridDim.x * blockDim.x;
  const int g = blockIdx.x * blockDim.x + threadIdx.x;
  for (int i = g; i < kH3 * kDin; i += stride) wi0b[i] = f2b(Wi0[i]);
  for (int i = g; i < kH3 * kH; i += stride) {
    wh0b[i] = f2b(Wh0[i]); wi1b[i] = f2b(Wi1[i]); wh1b[i] = f2b(Wh1[i]);
  }
  for (int i = g; i < kB * kT * kDin; i += stride) xb[i] = f2b(x[i]);
  for (int i = g; i < 2 * kB * kH; i += stride) { h0b[i] = 0; h1b[i] = 0; }
  for (int i = g; i < kH; i += stride) {
    bias[0 * kH + i] = bi0[0 * kH + i] + bh0[0 * kH + i];  // r combined
    bias[1 * kH + i] = bi0[1 * kH + i] + bh0[1 * kH + i];  // z combined
    bias[2 * kH + i] = bi0[2 * kH + i];                    // i_n
    bias[3 * kH + i] = bh0[2 * kH + i];                    // h_n
    bias[4 * kH + i] = bi1[0 * kH + i] + bh1[0 * kH + i];
    bias[5 * kH + i] = bi1[1 * kH + i] + bh1[1 * kH + i];
    bias[6 * kH + i] = bi1[2 * kH + i];
    bias[7 * kH + i] = bh1[2 * kH + i];
  }
  for (int i = g; i < 256; i += stride) slots[i] = 0;
}

// ---------------------------------------------------------------------------
// Persistent GRU kernel. Grid 256 x 256. Block=(jt,mt): 16 hidden units x
// 16 batch rows; 4 waves K-split, LDS reduce, gate math, 2 grid barriers/step.
// ---------------------------------------------------------------------------
__global__ void __launch_bounds__(256, 1) gru_main(
    const unsigned short* __restrict__ xb,
    const unsigned short* __restrict__ wi0, const unsigned short* __restrict__ wh0,
    const unsigned short* __restrict__ wi1, const unsigned short* __restrict__ wh1,
    const float* __restrict__ bias,
    unsigned short* __restrict__ h0b, unsigned short* __restrict__ h1b,
    unsigned* __restrict__ slots,
    const float* __restrict__ Wo, const float* __restrict__ bo,
    float* __restrict__ out) {
  __shared__ float red[4][4][64][5];  // [wave][gate][lane][reg(+pad)]

  const int tid  = threadIdx.x;
  const int lane = tid & 63;
  const int wv   = tid >> 6;                 // wave id == K-split index

  // XCD swizzle: the 4 mt-blocks of one jt share weights -> same XCD (%8)
  const int xcd  = blockIdx.x & 7;
  const int slot = blockIdx.x >> 3;
  const int mt   = slot & 3;
  const int jt   = (slot >> 2) * 8 + xcd;    // 0..63

  const int ln15 = lane & 15;
  const int kg   = (lane >> 4) * 8;

  const int bA = mt * 16 + ln15;             // A-fragment batch row
  const int jr = jt * 16 + ln15;             // B-fragment hidden-unit row

  const unsigned short* wh0_r = wh0 + (size_t)(0 * kH + jr) * kH;
  const unsigned short* wh0_z = wh0 + (size_t)(1 * kH + jr) * kH;
  const unsigned short* wh0_n = wh0 + (size_t)(2 * kH + jr) * kH;
  const unsigned short* wi0_r = wi0 + (size_t)(0 * kH + jr) * kDin;
  const unsigned short* wi0_z = wi0 + (size_t)(1 * kH + jr) * kDin;
  const unsigned short* wi0_n = wi0 + (size_t)(2 * kH + jr) * kDin;
  const unsigned short* wi1_r = wi1 + (size_t)(0 * kH + jr) * kH;
  const unsigned short* wi1_z = wi1 + (size_t)(1 * kH + jr) * kH;
  const unsigned short* wi1_n = wi1 + (size_t)(2 * kH + jr) * kH;
  const unsigned short* wh1_r = wh1 + (size_t)(0 * kH + jr) * kH;
  const unsigned short* wh1_z = wh1 + (size_t)(1 * kH + jr) * kH;
  const unsigned short* wh1_n = wh1 + (size_t)(2 * kH + jr) * kH;

  // reduce-phase mapping: C/D frag col=lane&15 (j), row=(lane>>4)*4+reg (b)
  const int jg = jt * 16 + (lane & 15);
  const int bg = mt * 16 + ((lane >> 4) * 4 + wv);

  const f32x4 z4 = {0.f, 0.f, 0.f, 0.f};
  unsigned phase = 0;

  for (int t = 0; t < kT; ++t) {
    const int cur = t & 1;
    const unsigned short* h0c = h0b + cur * (kB * kH);
    unsigned short*       h0n = h0b + (1 - cur) * (kB * kH);
    const unsigned short* h1c = h1b + cur * (kB * kH);
    unsigned short*       h1n = h1b + (1 - cur) * (kB * kH);

    // ---------------- layer 0: gh0 (K=1024 split 4) + gi0 (K=256 split 4) --
    f32x4 ar = z4, az = z4, ai = z4, ah = z4;
    {
      const unsigned short* ap = h0c + bA * kH + wv * 256 + kg;
      const unsigned short* br = wh0_r + wv * 256 + kg;
      const unsigned short* bz = wh0_z + wv * 256 + kg;
      const unsigned short* bn = wh0_n + wv * 256 + kg;
#pragma unroll
      for (int ks = 0; ks < 8; ++ks) {
        bf16x8 a = ld8(ap + ks * 32);
        ar = MFMA16(a, ld8(br + ks * 32), ar);
        az = MFMA16(a, ld8(bz + ks * 32), az);
        ah = MFMA16(a, ld8(bn + ks * 32), ah);
      }
      const unsigned short* xp = xb + (size_t)bA * (kT * kDin) + t * kDin + wv * 64 + kg;
      const unsigned short* cr = wi0_r + wv * 64 + kg;
      const unsigned short* cz = wi0_z + wv * 64 + kg;
      const unsigned short* cn = wi0_n + wv * 64 + kg;
#pragma unroll
      for (int ks = 0; ks < 2; ++ks) {
        bf16x8 a = ld8(xp + ks * 32);
        ar = MFMA16(a, ld8(cr + ks * 32), ar);
        az = MFMA16(a, ld8(cz + ks * 32), az);
        ai = MFMA16(a, ld8(cn + ks * 32), ai);
      }
    }
#pragma unroll
    for (int q = 0; q < 4; ++q) {
      red[wv][0][lane][q] = ar[q]; red[wv][1][lane][q] = az[q];
      red[wv][2][lane][q] = ai[q]; red[wv][3][lane][q] = ah[q];
    }
    __syncthreads();
    {
      float sr = 0, sz = 0, si = 0, sh = 0;
#pragma unroll
      for (int w = 0; w < 4; ++w) {
        sr += red[w][0][lane][wv]; sz += red[w][1][lane][wv];
        si += red[w][2][lane][wv]; sh += red[w][3][lane][wv];
      }
      float rg = sigmoidf_(sr + bias[0 * kH + jg]);
      float zg = sigmoidf_(sz + bias[1 * kH + jg]);
      float ng = tanhf(si + bias[2 * kH + jg] + rg * (sh + bias[3 * kH + jg]));
      float hp = b2f(h0c[bg * kH + jg]);
      h0n[bg * kH + jg] = f2b((1.f - zg) * ng + zg * hp);
    }
    ++phase;
    grid_barrier(slots, phase);

    // ---------------- layer 1: gi1(h0_new) + gh1(h1), each K=1024 split 4 --
    ar = z4; az = z4; ai = z4; ah = z4;
    {
      const unsigned short* a0p = h0n + bA * kH + wv * 256 + kg;
      const unsigned short* a1p = h1c + bA * kH + wv * 256 + kg;
      const unsigned short* pr = wi1_r + wv * 256 + kg;
      const unsigned short* pz = wi1_z + wv * 256 + kg;
      const unsigned short* pn = wi1_n + wv * 256 + kg;
      const unsigned short* qr = wh1_r + wv * 256 + kg;
      const unsigned short* qz = wh1_z + wv * 256 + kg;
      const unsigned short* qn = wh1_n + wv * 256 + kg;
#pragma unroll
      for (int ks = 0; ks < 8; ++ks) {
        bf16x8 a0 = ld8(a0p + ks * 32);
        ar = MFMA16(a0, ld8(pr + ks * 32), ar);
        az = MFMA16(a0, ld8(pz + ks * 32), az);
        ai = MFMA16(a0, ld8(pn + ks * 32), ai);
        bf16x8 a1 = ld8(a1p + ks * 32);
        ar = MFMA16(a1, ld8(qr + ks * 32), ar);
        az = MFMA16(a1, ld8(qz + ks * 32), az);
        ah = MFMA16(a1, ld8(qn + ks * 32), ah);
      }
    }
#pragma unroll
    for (int q = 0; q < 4; ++q) {
      red[wv][0][lane][q] = ar[q]; red[wv][1][lane][q] = az[q];
      red[wv][2][lane][q] = ai[q]; red[wv][3][lane][q] = ah[q];
    }
    __syncthreads();
    {
      float sr = 0, sz = 0, si = 0, sh = 0;
#pragma unroll
      for (int w = 0; w < 4; ++w) {
        sr += red[w][0][lane][wv]; sz += red[w][1][lane][wv];
        si += red[w][2][lane][wv]; sh += red[w][3][lane][wv];
      }
      float rg = sigmoidf_(sr + bias[4 * kH + jg]);
      float zg = sigmoidf_(sz + bias[5 * kH + jg]);
      float ng = tanhf(si + bias[6 * kH + jg] + rg * (sh + bias[7 * kH + jg]));
      float hp = b2f(h1c[bg * kH + jg]);
      h1n[bg * kH + jg] = f2b((1.f - zg) * ng + zg * hp);
    }
    ++phase;
    grid_barrier(slots, phase);
  }

  // ---------------- output projection: out = h1 @ Wo^T + bo (fp32) ---------
  // final h1 lives in buffer 0 (t=511 is odd: writes buf 1-(511&1)=0)
  const int idx = blockIdx.x * 256 + tid;
  if (idx < kB * kDout) {
    const int b = idx >> 8;
    const int o = idx & 255;
    const unsigned short* hrow = h1b + b * kH;
    const float* wrow = Wo + (size_t)o * kH;
    float acc = bo[o];
#pragma unroll 4
    for (int k = 0; k < kH; k += 4) {
      float4 w4 = *reinterpret_cast<const float4*>(wrow + k);
      acc += b2f(hrow[k + 0]) * w4.x + b2f(hrow[k + 1]) * w4.y +
             b2f(hrow[k + 2]) * w4.z + b2f(hrow[k + 3]) * w4.w;
    }
    out[idx] = acc;
  }
}

// ---------------------------------------------------------------------------
extern "C" void kernel_launch(void* const* d_in, const int* in_sizes, int n_in,
                              void* d_out, int out_size, void* d_ws, size_t ws_size,
                              hipStream_t stream) {
  const float* x   = (const float*)d_in[0];
  const float* Wi0 = (const float*)d_in[1];
  const float* Wh0 = (const float*)d_in[2];
  const float* bi0 = (const float*)d_in[3];
  const float* bh0 = (const float*)d_in[4];
  const float* Wi1 = (const float*)d_in[5];
  const float* Wh1 = (const float*)d_in[6];
  const float* bi1 = (const float*)d_in[7];
  const float* bh1 = (const float*)d_in[8];
  const float* Wo  = (const float*)d_in[9];
  const float* bo  = (const float*)d_in[10];

  char* ws = (char*)d_ws;
  size_t off = 0;
  auto take = [&](size_t bytes) {
    size_t r = off;
    off += (bytes + 255) & ~(size_t)255;
    return r;
  };
  unsigned*       slots = (unsigned*)(ws + take(256 * sizeof(unsigned)));
  unsigned short* xb    = (unsigned short*)(ws + take((size_t)kB * kT * kDin * 2));
  unsigned short* wi0b  = (unsigned short*)(ws + take((size_t)kH3 * kDin * 2));
  unsigned short* wh0b  = (unsigned short*)(ws + take((size_t)kH3 * kH * 2));
  unsigned short* wi1b  = (unsigned short*)(ws + take((size_t)kH3 * kH * 2));
  unsigned short* wh1b  = (unsigned short*)(ws + take((size_t)kH3 * kH * 2));
  unsigned short* h0b   = (unsigned short*)(ws + take((size_t)2 * kB * kH * 2));
  unsigned short* h1b   = (unsigned short*)(ws + take((size_t)2 * kB * kH * 2));
  float*          bias  = (float*)(ws + take(8 * kH * sizeof(float)));

  gru_prep<<<2048, 256, 0, stream>>>(x, Wi0, Wh0, bi0, bh0, Wi1, Wh1, bi1, bh1,
                                     xb, wi0b, wh0b, wi1b, wh1b, h0b, h1b, bias,
                                     slots);
  gru_main<<<256, 256, 0, stream>>>(xb, wi0b, wh0b, wi1b, wh1b, bias, h0b, h1b,
                                    slots, Wo, bo, (float*)d_out);
}

// Round 2
// 10101.250 us; speedup vs baseline: 4.6822x; 4.6822x over previous
//
#include <hip/hip_runtime.h>

// Problem dims
constexpr int kB    = 64;
constexpr int kT    = 512;
constexpr int kDin  = 256;
constexpr int kH    = 1024;
constexpr int kH3   = 3072;
constexpr int kDout = 256;
constexpr int kHU   = kH / 2;      // uints per h row (2 bf16 per uint)
constexpr int kHOFS = kB * kHU;    // uints per h buffer

typedef float  f32x4  __attribute__((ext_vector_type(4)));
typedef __bf16 bf16x8 __attribute__((ext_vector_type(8)));

__device__ __forceinline__ float b2f(unsigned short u) {
  union { float f; unsigned u32; } c; c.u32 = ((unsigned)u) << 16; return c.f;
}
__device__ __forceinline__ unsigned short f2b(float f) {
  union { float f; unsigned u32; } c; c.f = f;
  unsigned r = c.u32 + 0x7fffu + ((c.u32 >> 16) & 1u);  // RNE
  return (unsigned short)(r >> 16);
}
__device__ __forceinline__ bf16x8 ld8(const unsigned short* p) {
  return *reinterpret_cast<const bf16x8*>(p);
}
// Coherent (sc1, L1/L2-bypassing) 16B h-state fragment load: 2x 8B atomics.
__device__ __forceinline__ bf16x8 ld8a(const unsigned* p) {
  union { unsigned long long u[2]; bf16x8 v; } c;
  c.u[0] = __hip_atomic_load((const unsigned long long*)p, __ATOMIC_RELAXED,
                             __HIP_MEMORY_SCOPE_AGENT);
  c.u[1] = __hip_atomic_load((const unsigned long long*)(p + 2), __ATOMIC_RELAXED,
                             __HIP_MEMORY_SCOPE_AGENT);
  return c.v;
}
__device__ __forceinline__ float sigm_(float x) {
  return 1.f / (1.f + __expf(-x));
}
__device__ __forceinline__ float tanh_(float x) {
  // tanh(x) = 1 - 2/(e^{2x}+1); saturates correctly for |x| large
  return 1.f - 2.f / (__expf(2.f * x) + 1.f);
}

#define MFMA16(a, b, c) __builtin_amdgcn_mfma_f32_16x16x32_bf16((a), (b), (c), 0, 0, 0)

// ---------------------------------------------------------------------------
// Prep: fp32->bf16 conversion, combined biases, zero h buffers + flag slots.
// ---------------------------------------------------------------------------
__global__ void gru_prep(const float* __restrict__ x,
                         const float* __restrict__ Wi0, const float* __restrict__ Wh0,
                         const float* __restrict__ bi0, const float* __restrict__ bh0,
                         const float* __restrict__ Wi1, const float* __restrict__ Wh1,
                         const float* __restrict__ bi1, const float* __restrict__ bh1,
                         unsigned short* __restrict__ xb,
                         unsigned short* __restrict__ wi0b, unsigned short* __restrict__ wh0b,
                         unsigned short* __restrict__ wi1b, unsigned short* __restrict__ wh1b,
                         unsigned* __restrict__ h0u, unsigned* __restrict__ h1u,
                         float* __restrict__ bias, unsigned* __restrict__ slots) {
  const int stride = gridDim.x * blockDim.x;
  const int g = blockIdx.x * blockDim.x + threadIdx.x;
  for (int i = g; i < kH3 * kDin; i += stride) wi0b[i] = f2b(Wi0[i]);
  for (int i = g; i < kH3 * kH; i += stride) {
    wh0b[i] = f2b(Wh0[i]); wi1b[i] = f2b(Wi1[i]); wh1b[i] = f2b(Wh1[i]);
  }
  for (int i = g; i < kB * kT * kDin; i += stride) xb[i] = f2b(x[i]);
  for (int i = g; i < 2 * kHOFS; i += stride) { h0u[i] = 0; h1u[i] = 0; }
  for (int i = g; i < kH; i += stride) {
    bias[0 * kH + i] = bi0[0 * kH + i] + bh0[0 * kH + i];
    bias[1 * kH + i] = bi0[1 * kH + i] + bh0[1 * kH + i];
    bias[2 * kH + i] = bi0[2 * kH + i];
    bias[3 * kH + i] = bh0[2 * kH + i];
    bias[4 * kH + i] = bi1[0 * kH + i] + bh1[0 * kH + i];
    bias[5 * kH + i] = bi1[1 * kH + i] + bh1[1 * kH + i];
    bias[6 * kH + i] = bi1[2 * kH + i];
    bias[7 * kH + i] = bh1[2 * kH + i];
  }
  for (int i = g; i < 256; i += stride) slots[i] = 0;
}

// ---------------------------------------------------------------------------
// Persistent pipelined GRU. Grid 256 x 512. Waves 0-3: layer0 tick t;
// waves 4-7: layer1 tick t-1 (pipeline skew). One grid barrier per tick.
// All cross-block traffic (h state, flags) via relaxed AGENT atomics (sc1,
// IF-coherent) -> NO fences -> weights stay L2-resident all 513 ticks.
// ---------------------------------------------------------------------------
__global__ void __launch_bounds__(512, 2) gru_main(
    const unsigned short* __restrict__ xb,
    const unsigned short* __restrict__ wi0, const unsigned short* __restrict__ wh0,
    const unsigned short* __restrict__ wi1, const unsigned short* __restrict__ wh1,
    const float* __restrict__ bias,
    unsigned* __restrict__ h0u, unsigned* __restrict__ h1u,
    unsigned* __restrict__ slots,
    const float* __restrict__ Wo, const float* __restrict__ bo,
    float* __restrict__ out) {
  __shared__ float red[2][4][4][64][5];  // [layer][kw][gate][lane][reg(+pad)]
  __shared__ unsigned hstage[2][kHU];    // output-projection staging

  const int tid   = threadIdx.x;
  const int lane  = tid & 63;
  const int wv    = tid >> 6;        // 0..7
  const int layer = wv >> 2;         // 0: L0, 1: L1
  const int kw    = wv & 3;          // K-split index within layer

  // XCD swizzle: 4 mt-blocks sharing a jt weight slice land on one XCD
  const int xcd  = blockIdx.x & 7;
  const int slot = blockIdx.x >> 3;
  const int mt   = slot & 3;
  const int jt   = (slot >> 2) * 8 + xcd;

  const int ln15 = lane & 15;
  const int kgE  = (lane >> 4) * 8;          // element offset in K-chunk
  const int ucol = (lane >> 4) * 4;          // uint offset in K-chunk
  const int bA   = mt * 16 + ln15;           // A-fragment batch row
  const int jr   = jt * 16 + ln15;           // B-fragment hidden-unit row

  // per-layer weight row pointers (plain cached loads; never invalidated)
  const unsigned short* whb = (layer == 0) ? wh0 : wh1;  // recurrent (-> ah)
  const unsigned short* wib = (layer == 0) ? wi0 : wi1;  // input (-> ai)
  const int wiK = (layer == 0) ? kDin : kH;
  const unsigned short* wh_r = whb + (size_t)(0 * kH + jr) * kH;
  const unsigned short* wh_z = whb + (size_t)(1 * kH + jr) * kH;
  const unsigned short* wh_n = whb + (size_t)(2 * kH + jr) * kH;
  const unsigned short* wi_r = wib + (size_t)(0 * kH + jr) * wiK;
  const unsigned short* wi_z = wib + (size_t)(1 * kH + jr) * wiK;
  const unsigned short* wi_n = wib + (size_t)(2 * kH + jr) * wiK;

  // C/D frag: col=lane&15 (j), row=(lane>>4)*4+reg (b); reduce thread owns reg=kw
  const int jg = jt * 16 + ln15;
  const int bg = mt * 16 + (lane >> 4) * 4 + kw;

  const f32x4 z4 = {0.f, 0.f, 0.f, 0.f};

  for (int t = 0; t <= kT; ++t) {
    const int rb0 = (t + 1) & 1, wb0 = t & 1;        // h0: read t-1, write t
    const int rb1 = t & 1,       wb1 = (t + 1) & 1;  // h1: read t-2, write t-1
    const bool active = (layer == 0) ? (t < kT) : (t >= 1);

    f32x4 ar = z4, az = z4, ai = z4, ah = z4;
    if (active) {
      if (layer == 0) {
        const unsigned* ap = h0u + rb0 * kHOFS + bA * kHU + kw * 128 + ucol;
        const unsigned short* br = wh_r + kw * 256 + kgE;
        const unsigned short* bz = wh_z + kw * 256 + kgE;
        const unsigned short* bn = wh_n + kw * 256 + kgE;
#pragma unroll
        for (int ks = 0; ks < 8; ++ks) {
          bf16x8 a = ld8a(ap + ks * 16);
          ar = MFMA16(a, ld8(br + ks * 32), ar);
          az = MFMA16(a, ld8(bz + ks * 32), az);
          ah = MFMA16(a, ld8(bn + ks * 32), ah);
        }
        const unsigned short* xp = xb + (size_t)bA * (kT * kDin) + t * kDin + kw * 64 + kgE;
        const unsigned short* cr = wi_r + kw * 64 + kgE;
        const unsigned short* cz = wi_z + kw * 64 + kgE;
        const unsigned short* cn = wi_n + kw * 64 + kgE;
#pragma unroll
        for (int ks = 0; ks < 2; ++ks) {
          bf16x8 a = ld8(xp + ks * 32);
          ar = MFMA16(a, ld8(cr + ks * 32), ar);
          az = MFMA16(a, ld8(cz + ks * 32), az);
          ai = MFMA16(a, ld8(cn + ks * 32), ai);
        }
      } else {
        const unsigned* a0 = h0u + rb0 * kHOFS + bA * kHU + kw * 128 + ucol;
        const unsigned* a1 = h1u + rb1 * kHOFS + bA * kHU + kw * 128 + ucol;
        const unsigned short* pr = wi_r + kw * 256 + kgE;
        const unsigned short* pz = wi_z + kw * 256 + kgE;
        const unsigned short* pn = wi_n + kw * 256 + kgE;
        const unsigned short* qr = wh_r + kw * 256 + kgE;
        const unsigned short* qz = wh_z + kw * 256 + kgE;
        const unsigned short* qn = wh_n + kw * 256 + kgE;
#pragma unroll
        for (int ks = 0; ks < 8; ++ks) {
          bf16x8 a0v = ld8a(a0 + ks * 16);
          ar = MFMA16(a0v, ld8(pr + ks * 32), ar);
          az = MFMA16(a0v, ld8(pz + ks * 32), az);
          ai = MFMA16(a0v, ld8(pn + ks * 32), ai);
          bf16x8 a1v = ld8a(a1 + ks * 16);
          ar = MFMA16(a1v, ld8(qr + ks * 32), ar);
          az = MFMA16(a1v, ld8(qz + ks * 32), az);
          ah = MFMA16(a1v, ld8(qn + ks * 32), ah);
        }
      }
    }
#pragma unroll
    for (int q = 0; q < 4; ++q) {
      red[layer][kw][0][lane][q] = ar[q]; red[layer][kw][1][lane][q] = az[q];
      red[layer][kw][2][lane][q] = ai[q]; red[layer][kw][3][lane][q] = ah[q];
    }
    __syncthreads();

    if (active) {
      float sr = 0, sz = 0, si = 0, sh = 0;
#pragma unroll
      for (int w = 0; w < 4; ++w) {
        sr += red[layer][w][0][lane][kw]; sz += red[layer][w][1][lane][kw];
        si += red[layer][w][2][lane][kw]; sh += red[layer][w][3][lane][kw];
      }
      const float* bb = bias + layer * 4 * kH;
      float rg = sigm_(sr + bb[jg]);
      float zg = sigm_(sz + bb[kH + jg]);
      float ng = tanh_(si + bb[2 * kH + jg] + rg * (sh + bb[3 * kH + jg]));
      unsigned* hn_;
      const unsigned* hc_;
      if (layer == 0) { hn_ = h0u + wb0 * kHOFS; hc_ = h0u + rb0 * kHOFS; }
      else            { hn_ = h1u + wb1 * kHOFS; hc_ = h1u + rb1 * kHOFS; }
      unsigned pp = __hip_atomic_load(hc_ + bg * kHU + (jg >> 1), __ATOMIC_RELAXED,
                                      __HIP_MEMORY_SCOPE_AGENT);
      float hp = b2f((unsigned short)((jg & 1) ? (pp >> 16) : (pp & 0xffff)));
      float hv = (1.f - zg) * ng + zg * hp;
      float pv = __shfl_xor(hv, 1);
      if (!(ln15 & 1)) {
        unsigned pk = (unsigned)f2b(hv) | ((unsigned)f2b(pv) << 16);
        __hip_atomic_store(hn_ + bg * kHU + (jg >> 1), pk, __ATOMIC_RELAXED,
                           __HIP_MEMORY_SCOPE_AGENT);
      }
    }

    // ---- grid barrier (fence-free): syncthreads drains vmcnt; flags via sc1
    __syncthreads();
    if (tid == 0)
      __hip_atomic_store(&slots[blockIdx.x], (unsigned)(t + 1), __ATOMIC_RELAXED,
                         __HIP_MEMORY_SCOPE_AGENT);
    if (tid < 64) {
      const unsigned ph = (unsigned)(t + 1);
      const unsigned long long* p = (const unsigned long long*)(slots + tid * 4);
      for (;;) {
        unsigned long long a = __hip_atomic_load(p, __ATOMIC_RELAXED,
                                                 __HIP_MEMORY_SCOPE_AGENT);
        unsigned long long b = __hip_atomic_load(p + 1, __ATOMIC_RELAXED,
                                                 __HIP_MEMORY_SCOPE_AGENT);
        if ((unsigned)a >= ph && (unsigned)(a >> 32) >= ph &&
            (unsigned)b >= ph && (unsigned)(b >> 32) >= ph) break;
        __builtin_amdgcn_s_sleep(2);
      }
    }
    __syncthreads();
  }

  // ---- output projection: out = h1[511] @ Wo^T + bo (h1 final in buf 1) ----
  if (blockIdx.x < 32) {
    const unsigned* hrow = h1u + 1 * kHOFS + (blockIdx.x * 2) * kHU;
    unsigned long long v = __hip_atomic_load((const unsigned long long*)hrow + tid,
                                             __ATOMIC_RELAXED, __HIP_MEMORY_SCOPE_AGENT);
    hstage[tid >> 8][(tid & 255) * 2 + 0] = (unsigned)v;
    hstage[tid >> 8][(tid & 255) * 2 + 1] = (unsigned)(v >> 32);
    __syncthreads();
    const int b = blockIdx.x * 2 + (tid >> 8);
    const int o = tid & 255;
    const float* wrow = Wo + (size_t)o * kH;
    const unsigned* hs = hstage[tid >> 8];
    float acc = bo[o];
#pragma unroll 8
    for (int u = 0; u < kHU; u += 2) {
      float4 w4 = *reinterpret_cast<const float4*>(wrow + u * 2);
      unsigned p0 = hs[u], p1 = hs[u + 1];
      acc += b2f((unsigned short)(p0 & 0xffff)) * w4.x +
             b2f((unsigned short)(p0 >> 16))    * w4.y +
             b2f((unsigned short)(p1 & 0xffff)) * w4.z +
             b2f((unsigned short)(p1 >> 16))    * w4.w;
    }
    out[b * kDout + o] = acc;
  }
}

// ---------------------------------------------------------------------------
extern "C" void kernel_launch(void* const* d_in, const int* in_sizes, int n_in,
                              void* d_out, int out_size, void* d_ws, size_t ws_size,
                              hipStream_t stream) {
  const float* x   = (const float*)d_in[0];
  const float* Wi0 = (const float*)d_in[1];
  const float* Wh0 = (const float*)d_in[2];
  const float* bi0 = (const float*)d_in[3];
  const float* bh0 = (const float*)d_in[4];
  const float* Wi1 = (const float*)d_in[5];
  const float* Wh1 = (const float*)d_in[6];
  const float* bi1 = (const float*)d_in[7];
  const float* bh1 = (const float*)d_in[8];
  const float* Wo  = (const float*)d_in[9];
  const float* bo  = (const float*)d_in[10];

  char* ws = (char*)d_ws;
  size_t off = 0;
  auto take = [&](size_t bytes) {
    size_t r = off;
    off += (bytes + 255) & ~(size_t)255;
    return r;
  };
  unsigned*       slots = (unsigned*)(ws + take(256 * sizeof(unsigned)));
  unsigned short* xb    = (unsigned short*)(ws + take((size_t)kB * kT * kDin * 2));
  unsigned short* wi0b  = (unsigned short*)(ws + take((size_t)kH3 * kDin * 2));
  unsigned short* wh0b  = (unsigned short*)(ws + take((size_t)kH3 * kH * 2));
  unsigned short* wi1b  = (unsigned short*)(ws + take((size_t)kH3 * kH * 2));
  unsigned short* wh1b  = (unsigned short*)(ws + take((size_t)kH3 * kH * 2));
  unsigned*       h0u   = (unsigned*)(ws + take((size_t)2 * kHOFS * 4));
  unsigned*       h1u   = (unsigned*)(ws + take((size_t)2 * kHOFS * 4));
  float*          bias  = (float*)(ws + take(8 * kH * sizeof(float)));

  gru_prep<<<2048, 256, 0, stream>>>(x, Wi0, Wh0, bi0, bh0, Wi1, Wh1, bi1, bh1,
                                     xb, wi0b, wh0b, wi1b, wh1b, h0u, h1u, bias,
                                     slots);
  gru_main<<<256, 512, 0, stream>>>(xb, wi0b, wh0b, wi1b, wh1b, bias, h0u, h1u,
                                    slots, Wo, bo, (float*)d_out);
}